// Round 1
// baseline (35.307 us; speedup 1.0000x reference)
//
#include <hip/hip_runtime.h>
#include <math.h>

// Second-order cone projection over 3 fixed groups:
//   (d=4,  m=2,000,000)  floats [0, 8M)
//   (d=8,  m=1,000,000)  floats [8M, 16M)
//   (d=16, m=  500,000)  floats [16M, 24M)
// Per row [t, z...]: nz = max(||z||, 1e-12)
//   nz <= t+eps  -> identity
//   nz <= -t     -> zero
//   else         -> 0.5*(1 + t/nz) * [nz, z...]
// Memory-bound: 96 MB read + 96 MB write.

#define SOC_EPS 1e-12f

template<int D>
__device__ __forceinline__ void proj_row(const float* __restrict__ in,
                                         float* __restrict__ out,
                                         long long row, long long m) {
    if (row >= m) return;
    const float4* ip = reinterpret_cast<const float4*>(in) + row * (D / 4);
    float4* op = reinterpret_cast<float4*>(out) + row * (D / 4);

    float r[D];
#pragma unroll
    for (int i = 0; i < D / 4; ++i) {
        float4 v = ip[i];
        r[4 * i + 0] = v.x;
        r[4 * i + 1] = v.y;
        r[4 * i + 2] = v.z;
        r[4 * i + 3] = v.w;
    }

    float t = r[0];
    float ss = 0.0f;
#pragma unroll
    for (int j = 1; j < D; ++j) ss = fmaf(r[j], r[j], ss);
    float nz = fmaxf(sqrtf(ss), SOC_EPS);

    bool in_cone  = (nz <= t + SOC_EPS);
    bool in_polar = (nz <= -t);
    float c = 0.5f * (1.0f + t / nz);   // nz >= 1e-12 > 0, never div-by-0

    float o[D];
    o[0] = in_cone ? t : (in_polar ? 0.0f : c * nz);
#pragma unroll
    for (int j = 1; j < D; ++j)
        o[j] = in_cone ? r[j] : (in_polar ? 0.0f : c * r[j]);

#pragma unroll
    for (int i = 0; i < D / 4; ++i) {
        float4 v;
        v.x = o[4 * i + 0];
        v.y = o[4 * i + 1];
        v.z = o[4 * i + 2];
        v.w = o[4 * i + 3];
        op[i] = v;
    }
}

__global__ __launch_bounds__(256)
void SecondOrderConeProjector_kernel(const float* __restrict__ x,
                                     float* __restrict__ out,
                                     int nb0, int nb1,
                                     long long m0, long long m1, long long m2,
                                     long long off1, long long off2) {
    int b = blockIdx.x;
    if (b < nb0) {
        long long row = (long long)b * blockDim.x + threadIdx.x;
        proj_row<4>(x, out, row, m0);
    } else if (b < nb0 + nb1) {
        long long row = (long long)(b - nb0) * blockDim.x + threadIdx.x;
        proj_row<8>(x + off1, out + off1, row, m1);
    } else {
        long long row = (long long)(b - nb0 - nb1) * blockDim.x + threadIdx.x;
        proj_row<16>(x + off2, out + off2, row, m2);
    }
}

extern "C" void kernel_launch(void* const* d_in, const int* in_sizes, int n_in,
                              void* d_out, int out_size, void* d_ws, size_t ws_size,
                              hipStream_t stream) {
    const float* x = (const float*)d_in[0];
    float* out = (float*)d_out;

    const long long m0 = 2000000, m1 = 1000000, m2 = 500000;
    const long long off1 = 4 * m0;            // 8,000,000 floats
    const long long off2 = off1 + 8 * m1;     // 16,000,000 floats

    const int block = 256;
    const int nb0 = (int)((m0 + block - 1) / block);  // 7813
    const int nb1 = (int)((m1 + block - 1) / block);  // 3907
    const int nb2 = (int)((m2 + block - 1) / block);  // 1954
    const int grid = nb0 + nb1 + nb2;

    SecondOrderConeProjector_kernel<<<grid, block, 0, stream>>>(
        x, out, nb0, nb1, m0, m1, m2, off1, off2);
}